// Round 10
// baseline (2770.464 us; speedup 1.0000x reference)
//
#include <hip/hip_runtime.h>
#include <cstdint>
#include <cstddef>

#define B_    4
#define N_TOK 1029
#define C_    1024
#define H_    16
#define L_    8
#define HID_  4096
#define M_TOK (B_*N_TOK)   // 4116
#define MP2_  4352
#define TM0_  4096         // main M rows (16 tiles of 256)
#define PROWS 4224         // pbuf row stride (4096 + 128 tail)
#define KVB_  128
#define KVT2_ 9
#define KPAD_ 1152

typedef float f32x4 __attribute__((ext_vector_type(4)));
typedef short bf16x8 __attribute__((ext_vector_type(8)));

__device__ __forceinline__ uint16_t f2bf(float f) {
  uint32_t u = __float_as_uint(f);
  u += 0x7fffu + ((u >> 16) & 1u);
  return (uint16_t)(u >> 16);
}

__device__ __forceinline__ void async_copy16(const uint16_t* src, uint16_t* lds_dst) {
  __builtin_amdgcn_global_load_lds(
      (const __attribute__((address_space(1))) void*)src,
      (__attribute__((address_space(3))) void*)lds_dst, 16, 0, 0);
}

__device__ __forceinline__ int swz16(int row, int byte_in_row) {
  return row * 128 + (byte_in_row ^ ((row & 7) << 4));
}

// ---------------- fp32 -> bf16 (row-major) ----------------
__global__ __launch_bounds__(256)
void cvt_f32_bf16(const float* __restrict__ in, uint16_t* __restrict__ out, int n4) {
  int i = blockIdx.x * 256 + threadIdx.x;
  if (i < n4) {
    float4 v = reinterpret_cast<const float4*>(in)[i];
    uint64_t pk = (uint64_t)f2bf(v.x) | ((uint64_t)f2bf(v.y) << 16)
                | ((uint64_t)f2bf(v.z) << 32) | ((uint64_t)f2bf(v.w) << 48);
    reinterpret_cast<uint64_t*>(out)[i] = pk;
  }
}

// ---------------- LayerNorm: 0 = bf16 row-major out, 1 = fp32 out ----------------
template<int OUTMODE>
__global__ __launch_bounds__(256)
void ln_fwd(const float* __restrict__ x, const float* __restrict__ w,
            const float* __restrict__ b, void* __restrict__ outp) {
  const int row = blockIdx.x;
  const int tid = threadIdx.x;
  const float4 v = reinterpret_cast<const float4*>(x + (size_t)row * C_)[tid];
  float s  = v.x + v.y + v.z + v.w;
  float s2 = v.x*v.x + v.y*v.y + v.z*v.z + v.w*v.w;
  #pragma unroll
  for (int d = 1; d < 64; d <<= 1) {
    s  += __shfl_xor(s, d);
    s2 += __shfl_xor(s2, d);
  }
  __shared__ float red[8];
  const int wv = tid >> 6;
  if ((tid & 63) == 0) { red[wv] = s; red[wv + 4] = s2; }
  __syncthreads();
  s  = red[0] + red[1] + red[2] + red[3];
  s2 = red[4] + red[5] + red[6] + red[7];
  const float mu = s * (1.0f / C_);
  const float rs = rsqrtf(fmaxf(s2 * (1.0f / C_) - mu * mu, 0.0f) + 1e-6f);
  const float4 wv4 = reinterpret_cast<const float4*>(w)[tid];
  const float4 bv4 = reinterpret_cast<const float4*>(b)[tid];
  const float o0 = (v.x - mu) * rs * wv4.x + bv4.x;
  const float o1 = (v.y - mu) * rs * wv4.y + bv4.y;
  const float o2 = (v.z - mu) * rs * wv4.z + bv4.z;
  const float o3 = (v.w - mu) * rs * wv4.w + bv4.w;
  if (OUTMODE == 0) {
    uint64_t pk = (uint64_t)f2bf(o0) | ((uint64_t)f2bf(o1) << 16)
                | ((uint64_t)f2bf(o2) << 32) | ((uint64_t)f2bf(o3) << 48);
    reinterpret_cast<uint64_t*>((uint16_t*)outp + (size_t)row * C_)[tid] = pk;
  } else {
    float4 o; o.x = o0; o.y = o1; o.z = o2; o.w = o3;
    reinterpret_cast<float4*>((float*)outp + (size_t)row * C_)[tid] = o;
  }
}

// ---------------- epilogue helper (shared main/tail) ----------------
template<int EPI>
__device__ __forceinline__ void epi_store(int m, int col, float v, int Nn, int kc,
    const float* bias, uint16_t* outb, float* pbuf,
    uint16_t* Qp, uint16_t* Kp, uint16_t* VTp) {
  if (EPI == 3) {
    pbuf[((size_t)kc * PROWS + m) * Nn + col] = v;
  } else if (EPI == 1) {
    const float vb = v + bias[col];
    const float u = -1.5957691216f * (vb + 0.044715f * vb * vb * vb);
    const float g = vb * __builtin_amdgcn_rcpf(1.0f + __expf(u));
    outb[(size_t)m * Nn + col] = f2bf(g);
  } else {  // qkv split
    if (m < M_TOK) {
      const float vb = v + bias[col];
      const int which = col >> 10;
      const int h = (col >> 6) & 15;
      const int d = col & 63;
      const int b = m / N_TOK;
      const int key = m - b * N_TOK;
      const int bh = b * 16 + h;
      if (which == 0)      Qp[((size_t)bh * KPAD_ + key) * 64 + d] = f2bf(vb * 0.125f);
      else if (which == 1) Kp[((size_t)bh * KPAD_ + key) * 64 + d] = f2bf(vb);
      else                 VTp[((size_t)bh * 64 + d) * KPAD_ + key] = f2bf(vb);
    }
  }
}

// ---------------- 256x256 8-phase GEMM (m201-style) + fused 128-wide M-tail ----
template<int EPI, int SPLIT>
__global__ __launch_bounds__(512)
void gemm8p(const uint16_t* __restrict__ A, const uint16_t* __restrict__ W,
            const float* __restrict__ bias, uint16_t* __restrict__ outb,
            float* __restrict__ pbuf,
            uint16_t* __restrict__ Qp, uint16_t* __restrict__ Kp,
            uint16_t* __restrict__ VTp, int Nn, int Ktot) {
  const int nbn = Nn >> 8;
  const int MAIN = 16 * nbn * SPLIT;
  const int KC = Ktot / SPLIT;
  const int nwg = (int)gridDim.x;
  const int q8 = nwg >> 3, r8 = nwg & 7;
  const int xcd = (int)blockIdx.x & 7, pos = (int)blockIdx.x >> 3;
  const int wgid = (xcd < r8 ? xcd * (q8 + 1) : r8 * (q8 + 1) + (xcd - r8) * q8) + pos;
  const int tid = (int)threadIdx.x;

  if (wgid >= MAIN) {
    // ---------- tail: rows 4096..4223, 128x128 register path ----------
    if (tid >= 256) return;
    const int tailid = wgid - MAIN;
    const int tnb = Nn >> 7;
    const int tbn = tailid % tnb, tkc = tailid / tnb;
    const int l = tid & 63, w2 = tid >> 6;
    const int l15 = l & 15, l4 = l >> 4;
    const int wr = w2 >> 1, wc = w2 & 1;
    const uint16_t* Ag = A + (size_t)(TM0_ + wr * 64) * Ktot + (size_t)tkc * KC;
    const uint16_t* Wg = W + (size_t)(tbn * 128 + wc * 64) * Ktot + (size_t)tkc * KC;
    f32x4 acc[4][4] = {};
    const int ks = KC >> 5;
    for (int s = 0; s < ks; ++s) {
      bf16x8 af[4], bf[4];
      #pragma unroll
      for (int i = 0; i < 4; ++i)
        af[i] = *(const bf16x8*)(Ag + (size_t)(i * 16 + l15) * Ktot + s * 32 + l4 * 8);
      #pragma unroll
      for (int j = 0; j < 4; ++j)
        bf[j] = *(const bf16x8*)(Wg + (size_t)(j * 16 + l15) * Ktot + s * 32 + l4 * 8);
      #pragma unroll
      for (int i = 0; i < 4; ++i)
        #pragma unroll
        for (int j = 0; j < 4; ++j)
          acc[i][j] = __builtin_amdgcn_mfma_f32_16x16x32_bf16(af[i], bf[j], acc[i][j], 0, 0, 0);
    }
    #pragma unroll
    for (int j = 0; j < 4; ++j) {
      const int col = tbn * 128 + wc * 64 + j * 16 + l15;
      #pragma unroll
      for (int i = 0; i < 4; ++i) {
        #pragma unroll
        for (int r = 0; r < 4; ++r) {
          const int m = TM0_ + wr * 64 + i * 16 + l4 * 4 + r;
          epi_store<EPI>(m, col, acc[i][j][r], Nn, tkc, bias, outb, pbuf, Qp, Kp, VTp);
        }
      }
    }
    return;
  }

  // ---------- main 8-phase path ----------
  __shared__ char lds[131072];
  const int kc  = (SPLIT > 1) ? wgid / (16 * nbn) : 0;
  const int rem = (SPLIT > 1) ? wgid % (16 * nbn) : wgid;
  const int bm = rem & 15, bn = rem >> 4;
  const int l = tid & 63, w = tid >> 6;
  const int l15 = l & 15, l4 = l >> 4;
  const int wr = w >> 2, wc = w & 3;

  const uint16_t* Ag = A + (size_t)bm * 256 * Ktot + (size_t)kc * KC;
  const uint16_t* Wg = W + (size_t)bn * 256 * Ktot + (size_t)kc * KC;

  const int srow = tid >> 3;
  const int schunk = (tid & 7) ^ (srow & 7);
  auto stage = [&](int mat, int j, int toff, int pdst) {
    const int rbase = mat ? (j * 64) : ((j & 1) * 128 + ((j >> 1)) * 64);
    const uint16_t* src = (mat ? Wg : Ag)
        + (size_t)(rbase + srow) * Ktot + toff + schunk * 8;
    uint16_t* dst = (uint16_t*)(lds + pdst * 65536 + mat * 32768 + rbase * 128 + tid * 16);
    async_copy16(src, dst);
  };

  const int csel0 = ((l4) ^ (l15 & 7)) * 16;
  const int csel1 = ((4 + l4) ^ (l15 & 7)) * 16;

  f32x4 acc[8][4] = {};
  // prologue: tile 0 -> buf0 (order: B0..B3, A0,A1, A2,A3)
  stage(1, 0, 0, 0); stage(1, 1, 0, 0); stage(1, 2, 0, 0); stage(1, 3, 0, 0);
  stage(0, 0, 0, 0); stage(0, 1, 0, 0); stage(0, 2, 0, 0); stage(0, 3, 0, 0);

  const int nt = KC >> 6;
  bf16x8 bfr[2][4];
  for (int t = 0; t < nt; ++t) {
    const int p = t & 1;
    const char* base = lds + p * 65536;
    const int toff = (t + 1) * 64;
    const bool more = (t + 1 < nt);
    // ---- body 1 (mh0) ----
    asm volatile("s_waitcnt vmcnt(2)" ::: "memory");
    __builtin_amdgcn_sched_barrier(0);
    __builtin_amdgcn_s_barrier();
    bf16x8 afr[4][2];
    #pragma unroll
    for (int f = 0; f < 4; ++f) {
      const int rb = (wr * 128 + f * 16 + l15) * 128;
      afr[f][0] = *(const bf16x8*)(base + rb + csel0);
      afr[f][1] = *(const bf16x8*)(base + rb + csel1);
    }
    #pragma unroll
    for (int nf = 0; nf < 4; ++nf) {
      const int rb = 32768 + (wc * 64 + nf * 16 + l15) * 128;
      bfr[0][nf] = *(const bf16x8*)(base + rb + csel0);
      bfr[1][nf] = *(const bf16x8*)(base + rb + csel1);
    }
    if (more) {
      stage(1, 0, toff, p ^ 1); stage(1, 1, toff, p ^ 1);
      stage(1, 2, toff, p ^ 1); stage(1, 3, toff, p ^ 1);
      stage(0, 0, toff, p ^ 1); stage(0, 1, toff, p ^ 1);
    }
    __builtin_amdgcn_s_setprio(1);
    #pragma unroll
    for (int kk = 0; kk < 2; ++kk)
      #pragma unroll
      for (int f = 0; f < 4; ++f)
        #pragma unroll
        for (int nf = 0; nf < 4; ++nf)
          acc[f][nf] = __builtin_amdgcn_mfma_f32_16x16x32_bf16(afr[f][kk], bfr[kk][nf], acc[f][nf], 0, 0, 0);
    __builtin_amdgcn_s_setprio(0);
    // ---- body 2 (mh1) ----
    if (t == nt - 1) asm volatile("s_waitcnt vmcnt(0)" ::: "memory");
    else             asm volatile("s_waitcnt vmcnt(6)" ::: "memory");
    __builtin_amdgcn_sched_barrier(0);
    __builtin_amdgcn_s_barrier();
    #pragma unroll
    for (int f = 0; f < 4; ++f) {
      const int rb = (wr * 128 + 64 + f * 16 + l15) * 128;
      afr[f][0] = *(const bf16x8*)(base + rb + csel0);
      afr[f][1] = *(const bf16x8*)(base + rb + csel1);
    }
    if (more) { stage(0, 2, toff, p ^ 1); stage(0, 3, toff, p ^ 1); }
    __builtin_amdgcn_s_setprio(1);
    #pragma unroll
    for (int kk = 0; kk < 2; ++kk)
      #pragma unroll
      for (int f = 0; f < 4; ++f)
        #pragma unroll
        for (int nf = 0; nf < 4; ++nf)
          acc[4 + f][nf] = __builtin_amdgcn_mfma_f32_16x16x32_bf16(afr[f][kk], bfr[kk][nf], acc[4 + f][nf], 0, 0, 0);
    __builtin_amdgcn_s_setprio(0);
  }

  #pragma unroll
  for (int nf = 0; nf < 4; ++nf) {
    const int col = bn * 256 + wc * 64 + nf * 16 + l15;
    #pragma unroll
    for (int mf = 0; mf < 8; ++mf) {
      const int mb = bm * 256 + wr * 128 + mf * 16 + l4 * 4;
      #pragma unroll
      for (int r = 0; r < 4; ++r)
        epi_store<EPI>(mb + r, col, acc[mf][nf][r], Nn, kc, bias, outb, pbuf, Qp, Kp, VTp);
    }
  }
}

// ---------------- split-K reduce ----------------
template<int KCH>
__global__ __launch_bounds__(256)
void reduce_add(const float* __restrict__ pbuf, const float* __restrict__ bias,
                float* __restrict__ xbuf) {
  const int m = blockIdx.x;
  const int c4 = threadIdx.x;
  float4 s = reinterpret_cast<const float4*>(bias)[c4];
  #pragma unroll
  for (int kc = 0; kc < KCH; ++kc) {
    const float4 pv = reinterpret_cast<const float4*>(pbuf + ((size_t)kc * PROWS + m) * C_)[c4];
    s.x += pv.x; s.y += pv.y; s.z += pv.z; s.w += pv.w;
  }
  float4 x = reinterpret_cast<float4*>(xbuf + (size_t)m * C_)[c4];
  x.x += s.x; x.y += s.y; x.z += s.z; x.w += s.w;
  reinterpret_cast<float4*>(xbuf + (size_t)m * C_)[c4] = x;
}

// ---------------- Flash attention (swapped operands, q lane-local) ----------------
__global__ __launch_bounds__(256, 3)
void attn_fwd(const uint16_t* __restrict__ Qp, const uint16_t* __restrict__ Kp,
              const uint16_t* __restrict__ VTp, uint16_t* __restrict__ ob) {
  __shared__ uint16_t Ksm_[KVB_ * 64];
  __shared__ uint16_t Vsm_[64 * KVB_];
  __shared__ uint16_t Psm_[4][16 * 136];

  const int tid = (int)threadIdx.x;
  const int l = tid & 63, w = tid >> 6;
  const int l15 = l & 15, l4 = l >> 4;
  const int bh = (int)blockIdx.x;
  const int qt = (int)blockIdx.y;

  const uint16_t* Kb = Kp + (size_t)bh * KPAD_ * 64;
  const uint16_t* Vb = VTp + (size_t)bh * 64 * KPAD_;

  bf16x8 qf[2];
  {
    const int qrow = qt * 64 + w * 16 + l15;
    const uint16_t* qbase = Qp + ((size_t)bh * KPAD_ + qrow) * 64;
    qf[0] = *(const bf16x8*)(qbase + l4 * 8);
    qf[1] = *(const bf16x8*)(qbase + 32 + l4 * 8);
  }

  float mrow = -1e30f, lrow = 0.0f;
  f32x4 oacc[4] = {};

  const int krow_s = tid >> 3;
  const int kslot_s = (tid & 7) ^ (krow_s & 7);
  const int vd_s = tid >> 4;
  const int vslot_s = (tid & 15) ^ (vd_s & 15);

  for (int kt = 0; kt < KVT2_; ++kt) {
    const int key0 = kt * KVB_;
    __syncthreads();
    #pragma unroll
    for (int it = 0; it < 4; ++it) {
      const int row = it * 32 + krow_s;
      async_copy16(Kb + (size_t)(key0 + row) * 64 + kslot_s * 8,
                   Ksm_ + it * 2048 + tid * 8);
    }
    #pragma unroll
    for (int it = 0; it < 4; ++it) {
      const int d = it * 16 + vd_s;
      async_copy16(Vb + (size_t)d * KPAD_ + key0 + vslot_s * 8,
                   Vsm_ + it * 2048 + tid * 8);
    }
    __syncthreads();

    f32x4 s[8];
    #pragma unroll
    for (int kf = 0; kf < 8; ++kf) s[kf] = f32x4{0.f, 0.f, 0.f, 0.f};
    #pragma unroll
    for (int kk = 0; kk < 2; ++kk) {
      #pragma unroll
      for (int kf = 0; kf < 8; ++kf) {
        const bf16x8 kfrag = *(const bf16x8*)((const char*)Ksm_ + swz16(kf * 16 + l15, kk * 64 + l4 * 16));
        s[kf] = __builtin_amdgcn_mfma_f32_16x16x32_bf16(kfrag, qf[kk], s[kf], 0, 0, 0);
      }
    }
    if (kt == KVT2_ - 1) {
      #pragma unroll
      for (int kf = 0; kf < 8; ++kf)
        #pragma unroll
        for (int r = 0; r < 4; ++r)
          if (key0 + kf * 16 + l4 * 4 + r >= N_TOK) s[kf][r] = -1e30f;
    }
    float pmx = s[0][0];
    #pragma unroll
    for (int kf = 0; kf < 8; ++kf)
      #pragma unroll
      for (int r = 0; r < 4; ++r) pmx = fmaxf(pmx, s[kf][r]);
    pmx = fmaxf(pmx, __shfl_xor(pmx, 16));
    pmx = fmaxf(pmx, __shfl_xor(pmx, 32));
    if (!__all(pmx - mrow <= 8.0f)) {
      const float mi = fmaxf(mrow, pmx);
      const float sc = __expf(mrow - mi);
      mrow = mi;
      lrow *= sc;
      #pragma unroll
      for (int df = 0; df < 4; ++df)
        #pragma unroll
        for (int r = 0; r < 4; ++r) oacc[df][r] *= sc;
    }
    float psum = 0.0f;
    #pragma unroll
    for (int kf = 0; kf < 8; ++kf) {
      const float p0 = __expf(s[kf][0] - mrow);
      const float p1 = __expf(s[kf][1] - mrow);
      const float p2 = __expf(s[kf][2] - mrow);
      const float p3 = __expf(s[kf][3] - mrow);
      psum += (p0 + p1) + (p2 + p3);
      const uint64_t pk = (uint64_t)f2bf(p0) | ((uint64_t)f2bf(p1) << 16)
                        | ((uint64_t)f2bf(p2) << 32) | ((uint64_t)f2bf(p3) << 48);
      *(uint64_t*)(&Psm_[w][l15 * 136 + kf * 16 + l4 * 4]) = pk;
    }
    psum += __shfl_xor(psum, 16);
    psum += __shfl_xor(psum, 32);
    lrow += psum;
    #pragma unroll
    for (int kk = 0; kk < 4; ++kk) {
      const bf16x8 pf = *(const bf16x8*)(&Psm_[w][l15 * 136 + kk * 32 + l4 * 8]);
      #pragma unroll
      for (int df = 0; df < 4; ++df) {
        const int d = df * 16 + l15;
        const bf16x8 vfrag = *(const bf16x8*)(Vsm_ + d * KVB_ + (((kk * 4 + l4) ^ (d & 15)) * 8));
        oacc[df] = __builtin_amdgcn_mfma_f32_16x16x32_bf16(vfrag, pf, oacc[df], 0, 0, 0);
      }
    }
  }

  const int q = qt * 64 + w * 16 + l15;
  if (q < N_TOK) {
    const float inv = 1.0f / lrow;
    const int m = (bh >> 4) * N_TOK + q;
    const int hbase = (bh & 15) * 64;
    #pragma unroll
    for (int df = 0; df < 4; ++df)
      #pragma unroll
      for (int r = 0; r < 4; ++r) {
        const int c = hbase + df * 16 + l4 * 4 + r;
        ob[(size_t)m * C_ + c] = f2bf(oacc[df][r] * inv);
      }
  }
}

extern "C" void kernel_launch(void* const* d_in, const int* in_sizes, int n_in,
                              void* d_out, int out_size, void* d_ws, size_t ws_size,
                              hipStream_t stream) {
  const float* x_in   = (const float*)d_in[0];
  const float* ln1_w  = (const float*)d_in[1];
  const float* ln1_b  = (const float*)d_in[2];
  const float* qkv_w  = (const float*)d_in[3];
  const float* qkv_b  = (const float*)d_in[4];
  const float* proj_w = (const float*)d_in[5];
  const float* proj_b = (const float*)d_in[6];
  const float* ln2_w  = (const float*)d_in[7];
  const float* ln2_b  = (const float*)d_in[8];
  const float* fc1_w  = (const float*)d_in[9];
  const float* fc1_b  = (const float*)d_in[10];
  const float* fc2_w  = (const float*)d_in[11];
  const float* fc2_b  = (const float*)d_in[12];
  const float* norm_w = (const float*)d_in[13];
  const float* norm_b = (const float*)d_in[14];

  char* p = (char*)d_ws;
  float*    xbuf = (float*)p;     p += (size_t)MP2_ * C_ * 4;
  uint16_t* hbuf = (uint16_t*)p;  p += (size_t)MP2_ * C_ * 2;
  uint16_t* big  = (uint16_t*)p;  p += (size_t)MP2_ * HID_ * 2;
  uint16_t* wq   = (uint16_t*)p;  p += (size_t)L_ * 3 * C_ * C_ * 2;
  uint16_t* wp   = (uint16_t*)p;  p += (size_t)L_ * C_ * C_ * 2;
  uint16_t* w1   = (uint16_t*)p;  p += (size_t)L_ * HID_ * C_ * 2;
  uint16_t* w2   = (uint16_t*)p;  p += (size_t)L_ * C_ * HID_ * 2;
  uint16_t* qp   = (uint16_t*)p;  p += (size_t)64 * KPAD_ * 64 * 2;
  uint16_t* kp   = (uint16_t*)p;  p += (size_t)64 * KPAD_ * 64 * 2;
  uint16_t* vtp  = (uint16_t*)p;  p += (size_t)64 * 64 * KPAD_ * 2;
  float*    pbuf = (float*)p;     p += (size_t)4 * PROWS * C_ * 4;   // SEPARATE (no alias!)
  if ((size_t)(p - (char*)d_ws) > ws_size) return;

  hipMemcpyAsync(xbuf, x_in, (size_t)M_TOK * C_ * sizeof(float),
                 hipMemcpyDeviceToDevice, stream);

  auto cvt = [&](const float* src, uint16_t* dst, size_t n) {
    const int n4 = (int)(n / 4);
    cvt_f32_bf16<<<dim3((n4 + 255) / 256), dim3(256), 0, stream>>>(src, dst, n4);
  };
  cvt(qkv_w,  wq, (size_t)L_ * 3 * C_ * C_);
  cvt(proj_w, wp, (size_t)L_ * C_ * C_);
  cvt(fc1_w,  w1, (size_t)L_ * HID_ * C_);
  cvt(fc2_w,  w2, (size_t)L_ * C_ * HID_);

  for (int lyr = 0; lyr < L_; ++lyr) {
    ln_fwd<0><<<dim3(M_TOK), dim3(256), 0, stream>>>(
        xbuf, ln1_w + (size_t)lyr * C_, ln1_b + (size_t)lyr * C_, hbuf);
    gemm8p<0, 1><<<dim3(216), dim3(512), 0, stream>>>(
        hbuf, wq + (size_t)lyr * 3 * C_ * C_, qkv_b + (size_t)lyr * 3 * C_,
        nullptr, nullptr, qp, kp, vtp, 3 * C_, C_);
    attn_fwd<<<dim3(64, 17), dim3(256), 0, stream>>>(qp, kp, vtp, hbuf);
    gemm8p<3, 2><<<dim3(144), dim3(512), 0, stream>>>(
        hbuf, wp + (size_t)lyr * C_ * C_, nullptr,
        nullptr, pbuf, nullptr, nullptr, nullptr, C_, C_);
    reduce_add<2><<<dim3(M_TOK), dim3(256), 0, stream>>>(
        pbuf, proj_b + (size_t)lyr * C_, xbuf);
    ln_fwd<0><<<dim3(M_TOK), dim3(256), 0, stream>>>(
        xbuf, ln2_w + (size_t)lyr * C_, ln2_b + (size_t)lyr * C_, hbuf);
    gemm8p<1, 1><<<dim3(288), dim3(512), 0, stream>>>(
        hbuf, w1 + (size_t)lyr * HID_ * C_, fc1_b + (size_t)lyr * HID_,
        big, nullptr, nullptr, nullptr, nullptr, HID_, C_);
    gemm8p<3, 4><<<dim3(288), dim3(512), 0, stream>>>(
        big, w2 + (size_t)lyr * C_ * HID_, nullptr,
        nullptr, pbuf, nullptr, nullptr, nullptr, C_, HID_);
    reduce_add<4><<<dim3(M_TOK), dim3(256), 0, stream>>>(
        pbuf, fc2_b + (size_t)lyr * C_, xbuf);
  }
  ln_fwd<1><<<dim3(M_TOK), dim3(256), 0, stream>>>(xbuf, norm_w, norm_b, d_out);
}

// Round 11
// 2674.607 us; speedup vs baseline: 1.0358x; 1.0358x over previous
//
#include <hip/hip_runtime.h>
#include <cstdint>
#include <cstddef>

#define B_    4
#define N_TOK 1029
#define C_    1024
#define H_    16
#define L_    8
#define HID_  4096
#define M_TOK (B_*N_TOK)   // 4116
#define MP2_  4352
#define TM0_  4096         // gemm8p main M rows
#define PROWS 4224         // pbuf row stride; also gemm_s M extent (33*128)
#define KVB_  128
#define KVT2_ 9
#define KPAD_ 1152

typedef float f32x4 __attribute__((ext_vector_type(4)));
typedef short bf16x8 __attribute__((ext_vector_type(8)));

__device__ __forceinline__ uint16_t f2bf(float f) {
  uint32_t u = __float_as_uint(f);
  u += 0x7fffu + ((u >> 16) & 1u);
  return (uint16_t)(u >> 16);
}

__device__ __forceinline__ void async_copy16(const uint16_t* src, uint16_t* lds_dst) {
  __builtin_amdgcn_global_load_lds(
      (const __attribute__((address_space(1))) void*)src,
      (__attribute__((address_space(3))) void*)lds_dst, 16, 0, 0);
}

__device__ __forceinline__ int swz16(int row, int byte_in_row) {
  return row * 128 + (byte_in_row ^ ((row & 7) << 4));
}

// ---------------- fp32 -> bf16 (row-major) ----------------
__global__ __launch_bounds__(256)
void cvt_f32_bf16(const float* __restrict__ in, uint16_t* __restrict__ out, int n4) {
  int i = blockIdx.x * 256 + threadIdx.x;
  if (i < n4) {
    float4 v = reinterpret_cast<const float4*>(in)[i];
    uint64_t pk = (uint64_t)f2bf(v.x) | ((uint64_t)f2bf(v.y) << 16)
                | ((uint64_t)f2bf(v.z) << 32) | ((uint64_t)f2bf(v.w) << 48);
    reinterpret_cast<uint64_t*>(out)[i] = pk;
  }
}

// ---------------- LayerNorm (standalone; layer-0 ln1 only) ----------------
template<int OUTMODE>   // 0: bf16 out
__global__ __launch_bounds__(256)
void ln_fwd(const float* __restrict__ x, const float* __restrict__ w,
            const float* __restrict__ b, void* __restrict__ outp) {
  const int row = blockIdx.x;
  const int tid = threadIdx.x;
  const float4 v = reinterpret_cast<const float4*>(x + (size_t)row * C_)[tid];
  float s  = v.x + v.y + v.z + v.w;
  float s2 = v.x*v.x + v.y*v.y + v.z*v.z + v.w*v.w;
  #pragma unroll
  for (int d = 1; d < 64; d <<= 1) {
    s  += __shfl_xor(s, d);
    s2 += __shfl_xor(s2, d);
  }
  __shared__ float red[8];
  const int wv = tid >> 6;
  if ((tid & 63) == 0) { red[wv] = s; red[wv + 4] = s2; }
  __syncthreads();
  s  = red[0] + red[1] + red[2] + red[3];
  s2 = red[4] + red[5] + red[6] + red[7];
  const float mu = s * (1.0f / C_);
  const float rs = rsqrtf(fmaxf(s2 * (1.0f / C_) - mu * mu, 0.0f) + 1e-6f);
  const float4 wv4 = reinterpret_cast<const float4*>(w)[tid];
  const float4 bv4 = reinterpret_cast<const float4*>(b)[tid];
  const float o0 = (v.x - mu) * rs * wv4.x + bv4.x;
  const float o1 = (v.y - mu) * rs * wv4.y + bv4.y;
  const float o2 = (v.z - mu) * rs * wv4.z + bv4.z;
  const float o3 = (v.w - mu) * rs * wv4.w + bv4.w;
  uint64_t pk = (uint64_t)f2bf(o0) | ((uint64_t)f2bf(o1) << 16)
              | ((uint64_t)f2bf(o2) << 32) | ((uint64_t)f2bf(o3) << 48);
  reinterpret_cast<uint64_t*>((uint16_t*)outp + (size_t)row * C_)[tid] = pk;
}

// ---------------- fused split-K reduce + residual + LayerNorm ----------------
// xbuf[m,:] += bias + sum_kc pbuf[kc,m,:]; then LN(xbuf row) -> hbuf bf16 (OUT=0)
// or d_out fp32 (OUT=1).
template<int KCH, int OUT>
__global__ __launch_bounds__(256)
void reduce_ln(const float* __restrict__ pbuf, const float* __restrict__ bias,
               float* __restrict__ xbuf, const float* __restrict__ lw,
               const float* __restrict__ lb, void* __restrict__ outp) {
  const int m = blockIdx.x;
  const int c4 = threadIdx.x;
  float4 s = reinterpret_cast<const float4*>(bias)[c4];
  #pragma unroll
  for (int kc = 0; kc < KCH; ++kc) {
    const float4 pv = reinterpret_cast<const float4*>(pbuf + ((size_t)kc * PROWS + m) * C_)[c4];
    s.x += pv.x; s.y += pv.y; s.z += pv.z; s.w += pv.w;
  }
  float4 x = reinterpret_cast<float4*>(xbuf + (size_t)m * C_)[c4];
  x.x += s.x; x.y += s.y; x.z += s.z; x.w += s.w;
  reinterpret_cast<float4*>(xbuf + (size_t)m * C_)[c4] = x;
  // ---- LN on the new row ----
  float ss  = x.x + x.y + x.z + x.w;
  float ss2 = x.x*x.x + x.y*x.y + x.z*x.z + x.w*x.w;
  #pragma unroll
  for (int d = 1; d < 64; d <<= 1) {
    ss  += __shfl_xor(ss, d);
    ss2 += __shfl_xor(ss2, d);
  }
  __shared__ float red[8];
  const int wv = c4 >> 6;
  if ((c4 & 63) == 0) { red[wv] = ss; red[wv + 4] = ss2; }
  __syncthreads();
  ss  = red[0] + red[1] + red[2] + red[3];
  ss2 = red[4] + red[5] + red[6] + red[7];
  const float mu = ss * (1.0f / C_);
  const float rs = rsqrtf(fmaxf(ss2 * (1.0f / C_) - mu * mu, 0.0f) + 1e-6f);
  const float4 wv4 = reinterpret_cast<const float4*>(lw)[c4];
  const float4 bv4 = reinterpret_cast<const float4*>(lb)[c4];
  const float o0 = (x.x - mu) * rs * wv4.x + bv4.x;
  const float o1 = (x.y - mu) * rs * wv4.y + bv4.y;
  const float o2 = (x.z - mu) * rs * wv4.z + bv4.z;
  const float o3 = (x.w - mu) * rs * wv4.w + bv4.w;
  if (OUT == 0) {
    uint64_t pk = (uint64_t)f2bf(o0) | ((uint64_t)f2bf(o1) << 16)
                | ((uint64_t)f2bf(o2) << 32) | ((uint64_t)f2bf(o3) << 48);
    reinterpret_cast<uint64_t*>((uint16_t*)outp + (size_t)m * C_)[c4] = pk;
  } else {
    float4 o; o.x = o0; o.y = o1; o.z = o2; o.w = o3;
    reinterpret_cast<float4*>((float*)outp + (size_t)m * C_)[c4] = o;
  }
}

// ---------------- epilogue helper ----------------
// EPI 0: qkv head-split. EPI 1: GELU -> bf16 row-major. EPI 3: fp32 partial -> pbuf.
template<int EPI>
__device__ __forceinline__ void epi_store(int m, int col, float v, int Nn, int kc,
    const float* bias, uint16_t* outb, float* pbuf,
    uint16_t* Qp, uint16_t* Kp, uint16_t* VTp) {
  if (EPI == 3) {
    pbuf[((size_t)kc * PROWS + m) * C_ + col] = v;
  } else if (EPI == 1) {
    const float vb = v + bias[col];
    const float u = -1.5957691216f * (vb + 0.044715f * vb * vb * vb);
    const float g = vb * __builtin_amdgcn_rcpf(1.0f + __expf(u));
    outb[(size_t)m * Nn + col] = f2bf(g);
  } else {  // qkv split
    if (m < M_TOK) {
      const float vb = v + bias[col];
      const int which = col >> 10;
      const int h = (col >> 6) & 15;
      const int d = col & 63;
      const int b = m / N_TOK;
      const int key = m - b * N_TOK;
      const int bh = b * 16 + h;
      if (which == 0)      Qp[((size_t)bh * KPAD_ + key) * 64 + d] = f2bf(vb * 0.125f);
      else if (which == 1) Kp[((size_t)bh * KPAD_ + key) * 64 + d] = f2bf(vb);
      else                 VTp[((size_t)bh * 64 + d) * KPAD_ + key] = f2bf(vb);
    }
  }
}

// ---------------- gemm_s: 128x256, BK=64, 8 waves (2Mx4N, wave-tile 64x64) ------
// Single-buffered 48 KB LDS; launch_bounds(512,4) caps VGPR at 128 -> 2 blocks/CU
// (16 waves) for cross-block stage/compute stagger. M covered exactly: 33 tiles.
template<int EPI, int SPLIT>
__global__ __launch_bounds__(512, 4)
void gemm_s(const uint16_t* __restrict__ A, const uint16_t* __restrict__ W,
            const float* __restrict__ bias, uint16_t* __restrict__ outb,
            float* __restrict__ pbuf, int Nn, int Ktot) {
  const int nbn = Nn >> 8;
  const int KC = Ktot / SPLIT;
  const int nwg = (int)gridDim.x;
  const int q8 = nwg >> 3, r8 = nwg & 7;
  const int xcd = (int)blockIdx.x & 7, pos = (int)blockIdx.x >> 3;
  const int wgid = (xcd < r8 ? xcd * (q8 + 1) : r8 * (q8 + 1) + (xcd - r8) * q8) + pos;
  const int kc  = wgid / (33 * nbn);
  const int rem = wgid % (33 * nbn);
  const int bm = rem % 33, bn = rem / 33;   // bm fastest: per-XCD blocks share bn

  const int tid = (int)threadIdx.x;
  const int l = tid & 63, w = tid >> 6;
  const int l15 = l & 15, l4 = l >> 4;
  const int wr = w >> 2, wc = w & 3;

  __shared__ char lds[49152];   // A: [0,16K) 128 rows x 128B ; B: [16K,48K) 256 rows

  const uint16_t* Ag = A + (size_t)bm * 128 * Ktot + (size_t)kc * KC;
  const uint16_t* Wg = W + (size_t)bn * 256 * Ktot + (size_t)kc * KC;

  const int srow = tid >> 3;                 // 0..63
  const int schunk = (tid & 7) ^ (srow & 7); // source chunk for slot tid&7
  const int csel0 = ((l4) ^ (l15 & 7)) << 4;
  const int csel1 = ((4 + l4) ^ (l15 & 7)) << 4;

  f32x4 acc[4][4] = {};
  const int nt = KC >> 6;
  for (int t = 0; t < nt; ++t) {
    const int toff = t * 64;
    __syncthreads();   // all reads of buffer done
    #pragma unroll
    for (int j = 0; j < 2; ++j) {
      const int row = j * 64 + srow;
      async_copy16(Ag + (size_t)row * Ktot + toff + schunk * 8,
                   (uint16_t*)(lds + j * 8192 + tid * 16));
    }
    #pragma unroll
    for (int j = 0; j < 4; ++j) {
      const int row = j * 64 + srow;
      async_copy16(Wg + (size_t)row * Ktot + toff + schunk * 8,
                   (uint16_t*)(lds + 16384 + j * 8192 + tid * 16));
    }
    __syncthreads();   // staging drained (vmcnt0 before barrier)
    #pragma unroll
    for (int kk = 0; kk < 2; ++kk) {
      const int cs = kk ? csel1 : csel0;
      bf16x8 afr[4], bfr[4];
      #pragma unroll
      for (int f = 0; f < 4; ++f)
        afr[f] = *(const bf16x8*)(lds + (wr * 64 + f * 16 + l15) * 128 + cs);
      #pragma unroll
      for (int nf = 0; nf < 4; ++nf)
        bfr[nf] = *(const bf16x8*)(lds + 16384 + (wc * 64 + nf * 16 + l15) * 128 + cs);
      #pragma unroll
      for (int f = 0; f < 4; ++f)
        #pragma unroll
        for (int nf = 0; nf < 4; ++nf)
          acc[f][nf] = __builtin_amdgcn_mfma_f32_16x16x32_bf16(afr[f], bfr[nf], acc[f][nf], 0, 0, 0);
    }
  }

  #pragma unroll
  for (int nf = 0; nf < 4; ++nf) {
    const int col = bn * 256 + wc * 64 + nf * 16 + l15;
    #pragma unroll
    for (int mf = 0; mf < 4; ++mf) {
      const int mb = bm * 128 + wr * 64 + mf * 16 + l4 * 4;
      #pragma unroll
      for (int r = 0; r < 4; ++r)
        epi_store<EPI>(mb + r, col, acc[mf][nf][r], Nn, kc, bias, outb, pbuf,
                       nullptr, nullptr, nullptr);
    }
  }
}

// ---------------- gemm8p (qkv only): 256x256 8-phase + 128-wide M-tail ----------
template<int EPI, int SPLIT>
__global__ __launch_bounds__(512)
void gemm8p(const uint16_t* __restrict__ A, const uint16_t* __restrict__ W,
            const float* __restrict__ bias, uint16_t* __restrict__ outb,
            float* __restrict__ pbuf,
            uint16_t* __restrict__ Qp, uint16_t* __restrict__ Kp,
            uint16_t* __restrict__ VTp, int Nn, int Ktot) {
  const int nbn = Nn >> 8;
  const int MAIN = 16 * nbn * SPLIT;
  const int KC = Ktot / SPLIT;
  const int nwg = (int)gridDim.x;
  const int q8 = nwg >> 3, r8 = nwg & 7;
  const int xcd = (int)blockIdx.x & 7, pos = (int)blockIdx.x >> 3;
  const int wgid = (xcd < r8 ? xcd * (q8 + 1) : r8 * (q8 + 1) + (xcd - r8) * q8) + pos;
  const int tid = (int)threadIdx.x;

  if (wgid >= MAIN) {
    if (tid >= 256) return;
    const int tailid = wgid - MAIN;
    const int tnb = Nn >> 7;
    const int tbn = tailid % tnb, tkc = tailid / tnb;
    const int l = tid & 63, w2 = tid >> 6;
    const int l15 = l & 15, l4 = l >> 4;
    const int wr = w2 >> 1, wc = w2 & 1;
    const uint16_t* Ag = A + (size_t)(TM0_ + wr * 64) * Ktot + (size_t)tkc * KC;
    const uint16_t* Wg = W + (size_t)(tbn * 128 + wc * 64) * Ktot + (size_t)tkc * KC;
    f32x4 acc[4][4] = {};
    const int ks = KC >> 5;
    for (int s = 0; s < ks; ++s) {
      bf16x8 af[4], bf[4];
      #pragma unroll
      for (int i = 0; i < 4; ++i)
        af[i] = *(const bf16x8*)(Ag + (size_t)(i * 16 + l15) * Ktot + s * 32 + l4 * 8);
      #pragma unroll
      for (int j = 0; j < 4; ++j)
        bf[j] = *(const bf16x8*)(Wg + (size_t)(j * 16 + l15) * Ktot + s * 32 + l4 * 8);
      #pragma unroll
      for (int i = 0; i < 4; ++i)
        #pragma unroll
        for (int j = 0; j < 4; ++j)
          acc[i][j] = __builtin_amdgcn_mfma_f32_16x16x32_bf16(af[i], bf[j], acc[i][j], 0, 0, 0);
    }
    #pragma unroll
    for (int j = 0; j < 4; ++j) {
      const int col = tbn * 128 + wc * 64 + j * 16 + l15;
      #pragma unroll
      for (int i = 0; i < 4; ++i)
        #pragma unroll
        for (int r = 0; r < 4; ++r) {
          const int m = TM0_ + wr * 64 + i * 16 + l4 * 4 + r;
          epi_store<EPI>(m, col, acc[i][j][r], Nn, tkc, bias, outb, pbuf, Qp, Kp, VTp);
        }
    }
    return;
  }

  __shared__ char lds[131072];
  const int kc  = (SPLIT > 1) ? wgid / (16 * nbn) : 0;
  const int rem = (SPLIT > 1) ? wgid % (16 * nbn) : wgid;
  const int bm = rem & 15, bn = rem >> 4;
  const int l = tid & 63, w = tid >> 6;
  const int l15 = l & 15, l4 = l >> 4;
  const int wr = w >> 2, wc = w & 3;

  const uint16_t* Ag = A + (size_t)bm * 256 * Ktot + (size_t)kc * KC;
  const uint16_t* Wg = W + (size_t)bn * 256 * Ktot + (size_t)kc * KC;

  const int srow = tid >> 3;
  const int schunk = (tid & 7) ^ (srow & 7);
  auto stage = [&](int mat, int j, int toff, int pdst) {
    const int rbase = mat ? (j * 64) : ((j & 1) * 128 + ((j >> 1)) * 64);
    const uint16_t* src = (mat ? Wg : Ag)
        + (size_t)(rbase + srow) * Ktot + toff + schunk * 8;
    uint16_t* dst = (uint16_t*)(lds + pdst * 65536 + mat * 32768 + rbase * 128 + tid * 16);
    async_copy16(src, dst);
  };

  const int csel0 = ((l4) ^ (l15 & 7)) * 16;
  const int csel1 = ((4 + l4) ^ (l15 & 7)) * 16;

  f32x4 acc[8][4] = {};
  stage(1, 0, 0, 0); stage(1, 1, 0, 0); stage(1, 2, 0, 0); stage(1, 3, 0, 0);
  stage(0, 0, 0, 0); stage(0, 1, 0, 0); stage(0, 2, 0, 0); stage(0, 3, 0, 0);

  const int nt = KC >> 6;
  bf16x8 bfr[2][4];
  for (int t = 0; t < nt; ++t) {
    const int p = t & 1;
    const char* base = lds + p * 65536;
    const int toff = (t + 1) * 64;
    const bool more = (t + 1 < nt);
    asm volatile("s_waitcnt vmcnt(2)" ::: "memory");
    __builtin_amdgcn_sched_barrier(0);
    __builtin_amdgcn_s_barrier();
    bf16x8 afr[4][2];
    #pragma unroll
    for (int f = 0; f < 4; ++f) {
      const int rb = (wr * 128 + f * 16 + l15) * 128;
      afr[f][0] = *(const bf16x8*)(base + rb + csel0);
      afr[f][1] = *(const bf16x8*)(base + rb + csel1);
    }
    #pragma unroll
    for (int nf = 0; nf < 4; ++nf) {
      const int rb = 32768 + (wc * 64 + nf * 16 + l15) * 128;
      bfr[0][nf] = *(const bf16x8*)(base + rb + csel0);
      bfr[1][nf] = *(const bf16x8*)(base + rb + csel1);
    }
    if (more) {
      stage(1, 0, toff, p ^ 1); stage(1, 1, toff, p ^ 1);
      stage(1, 2, toff, p ^ 1); stage(1, 3, toff, p ^ 1);
      stage(0, 0, toff, p ^ 1); stage(0, 1, toff, p ^ 1);
    }
    __builtin_amdgcn_s_setprio(1);
    #pragma unroll
    for (int kk = 0; kk < 2; ++kk)
      #pragma unroll
      for (int f = 0; f < 4; ++f)
        #pragma unroll
        for (int nf = 0; nf < 4; ++nf)
          acc[f][nf] = __builtin_amdgcn_mfma_f32_16x16x32_bf16(afr[f][kk], bfr[kk][nf], acc[f][nf], 0, 0, 0);
    __builtin_amdgcn_s_setprio(0);
    if (t == nt - 1) asm volatile("s_waitcnt vmcnt(0)" ::: "memory");
    else             asm volatile("s_waitcnt vmcnt(6)" ::: "memory");
    __builtin_amdgcn_sched_barrier(0);
    __builtin_amdgcn_s_barrier();
    #pragma unroll
    for (int f = 0; f < 4; ++f) {
      const int rb = (wr * 128 + 64 + f * 16 + l15) * 128;
      afr[f][0] = *(const bf16x8*)(base + rb + csel0);
      afr[f][1] = *(const bf16x8*)(base + rb + csel1);
    }
    if (more) { stage(0, 2, toff, p ^ 1); stage(0, 3, toff, p ^ 1); }
    __builtin_amdgcn_s_setprio(1);
    #pragma unroll
    for (int kk = 0; kk < 2; ++kk)
      #pragma unroll
      for (int f = 0; f < 4; ++f)
        #pragma unroll
        for (int nf = 0; nf < 4; ++nf)
          acc[4 + f][nf] = __builtin_amdgcn_mfma_f32_16x16x32_bf16(afr[f][kk], bfr[kk][nf], acc[4 + f][nf], 0, 0, 0);
    __builtin_amdgcn_s_setprio(0);
  }

  #pragma unroll
  for (int nf = 0; nf < 4; ++nf) {
    const int col = bn * 256 + wc * 64 + nf * 16 + l15;
    #pragma unroll
    for (int mf = 0; mf < 8; ++mf) {
      const int mb = bm * 256 + wr * 128 + mf * 16 + l4 * 4;
      #pragma unroll
      for (int r = 0; r < 4; ++r)
        epi_store<EPI>(mb + r, col, acc[mf][nf][r], Nn, kc, bias, outb, pbuf, Qp, Kp, VTp);
    }
  }
}

// ---------------- Flash attention (swapped operands, q lane-local) ----------------
__global__ __launch_bounds__(256, 3)
void attn_fwd(const uint16_t* __restrict__ Qp, const uint16_t* __restrict__ Kp,
              const uint16_t* __restrict__ VTp, uint16_t* __restrict__ ob) {
  __shared__ uint16_t Ksm_[KVB_ * 64];
  __shared__ uint16_t Vsm_[64 * KVB_];
  __shared__ uint16_t Psm_[4][16 * 136];

  const int tid = (int)threadIdx.x;
  const int l = tid & 63, w = tid >> 6;
  const int l15 = l & 15, l4 = l >> 4;
  const int bh = (int)blockIdx.x;
  const int qt = (int)blockIdx.y;

  const uint16_t* Kb = Kp + (size_t)bh * KPAD_ * 64;
  const uint16_t* Vb = VTp + (size_t)bh * 64 * KPAD_;

  bf16x8 qf[2];
  {
    const int qrow = qt * 64 + w * 16 + l15;
    const uint16_t* qbase = Qp + ((size_t)bh * KPAD_ + qrow) * 64;
    qf[0] = *(const bf16x8*)(qbase + l4 * 8);
    qf[1] = *(const bf16x8*)(qbase + 32 + l4 * 8);
  }

  float mrow = -1e30f, lrow = 0.0f;
  f32x4 oacc[4] = {};

  const int krow_s = tid >> 3;
  const int kslot_s = (tid & 7) ^ (krow_s & 7);
  const int vd_s = tid >> 4;
  const int vslot_s = (tid & 15) ^ (vd_s & 15);

  for (int kt = 0; kt < KVT2_; ++kt) {
    const int key0 = kt * KVB_;
    __syncthreads();
    #pragma unroll
    for (int it = 0; it < 4; ++it) {
      const int row = it * 32 + krow_s;
      async_copy16(Kb + (size_t)(key0 + row) * 64 + kslot_s * 8,
                   Ksm_ + it * 2048 + tid * 8);
    }
    #pragma unroll
    for (int it = 0; it < 4; ++it) {
      const int d = it * 16 + vd_s;
      async_copy16(Vb + (size_t)d * KPAD_ + key0 + vslot_s * 8,
                   Vsm_ + it * 2048 + tid * 8);
    }
    __syncthreads();

    f32x4 s[8];
    #pragma unroll
    for (int kf = 0; kf < 8; ++kf) s[kf] = f32x4{0.f, 0.f, 0.f, 0.f};
    #pragma unroll
    for (int kk = 0; kk < 2; ++kk) {
      #pragma unroll
      for (int kf = 0; kf < 8; ++kf) {
        const bf16x8 kfrag = *(const bf16x8*)((const char*)Ksm_ + swz16(kf * 16 + l15, kk * 64 + l4 * 16));
        s[kf] = __builtin_amdgcn_mfma_f32_16x16x32_bf16(kfrag, qf[kk], s[kf], 0, 0, 0);
      }
    }
    if (kt == KVT2_ - 1) {
      #pragma unroll
      for (int kf = 0; kf < 8; ++kf)
        #pragma unroll
        for (int r = 0; r < 4; ++r)
          if (key0 + kf * 16 + l4 * 4 + r >= N_TOK) s[kf][r] = -1e30f;
    }
    float pmx = s[0][0];
    #pragma unroll
    for (int kf = 0; kf < 8; ++kf)
      #pragma unroll
      for (int r = 0; r < 4; ++r) pmx = fmaxf(pmx, s[kf][r]);
    pmx = fmaxf(pmx, __shfl_xor(pmx, 16));
    pmx = fmaxf(pmx, __shfl_xor(pmx, 32));
    if (!__all(pmx - mrow <= 8.0f)) {
      const float mi = fmaxf(mrow, pmx);
      const float sc = __expf(mrow - mi);
      mrow = mi;
      lrow *= sc;
      #pragma unroll
      for (int df = 0; df < 4; ++df)
        #pragma unroll
        for (int r = 0; r < 4; ++r) oacc[df][r] *= sc;
    }
    float psum = 0.0f;
    #pragma unroll
    for (int kf = 0; kf < 8; ++kf) {
      const float p0 = __expf(s[kf][0] - mrow);
      const float p1 = __expf(s[kf][1] - mrow);
      const float p2 = __expf(s[kf][2] - mrow);
      const float p3 = __expf(s[kf][3] - mrow);
      psum += (p0 + p1) + (p2 + p3);
      const uint64_t pk = (uint64_t)f2bf(p0) | ((uint64_t)f2bf(p1) << 16)
                        | ((uint64_t)f2bf(p2) << 32) | ((uint64_t)f2bf(p3) << 48);
      *(uint64_t*)(&Psm_[w][l15 * 136 + kf * 16 + l4 * 4]) = pk;
    }
    psum += __shfl_xor(psum, 16);
    psum += __shfl_xor(psum, 32);
    lrow += psum;
    #pragma unroll
    for (int kk = 0; kk < 4; ++kk) {
      const bf16x8 pf = *(const bf16x8*)(&Psm_[w][l15 * 136 + kk * 32 + l4 * 8]);
      #pragma unroll
      for (int df = 0; df < 4; ++df) {
        const int d = df * 16 + l15;
        const bf16x8 vfrag = *(const bf16x8*)(Vsm_ + d * KVB_ + (((kk * 4 + l4) ^ (d & 15)) * 8));
        oacc[df] = __builtin_amdgcn_mfma_f32_16x16x32_bf16(vfrag, pf, oacc[df], 0, 0, 0);
      }
    }
  }

  const int q = qt * 64 + w * 16 + l15;
  if (q < N_TOK) {
    const float inv = 1.0f / lrow;
    const int m = (bh >> 4) * N_TOK + q;
    const int hbase = (bh & 15) * 64;
    #pragma unroll
    for (int df = 0; df < 4; ++df)
      #pragma unroll
      for (int r = 0; r < 4; ++r) {
        const int c = hbase + df * 16 + l4 * 4 + r;
        ob[(size_t)m * C_ + c] = f2bf(oacc[df][r] * inv);
      }
  }
}

extern "C" void kernel_launch(void* const* d_in, const int* in_sizes, int n_in,
                              void* d_out, int out_size, void* d_ws, size_t ws_size,
                              hipStream_t stream) {
  const float* x_in   = (const float*)d_in[0];
  const float* ln1_w  = (const float*)d_in[1];
  const float* ln1_b  = (const float*)d_in[2];
  const float* qkv_w  = (const float*)d_in[3];
  const float* qkv_b  = (const float*)d_in[4];
  const float* proj_w = (const float*)d_in[5];
  const float* proj_b = (const float*)d_in[6];
  const float* ln2_w  = (const float*)d_in[7];
  const float* ln2_b  = (const float*)d_in[8];
  const float* fc1_w  = (const float*)d_in[9];
  const float* fc1_b  = (const float*)d_in[10];
  const float* fc2_w  = (const float*)d_in[11];
  const float* fc2_b  = (const float*)d_in[12];
  const float* norm_w = (const float*)d_in[13];
  const float* norm_b = (const float*)d_in[14];

  char* p = (char*)d_ws;
  float*    xbuf = (float*)p;     p += (size_t)MP2_ * C_ * 4;
  uint16_t* hbuf = (uint16_t*)p;  p += (size_t)MP2_ * C_ * 2;
  uint16_t* big  = (uint16_t*)p;  p += (size_t)MP2_ * HID_ * 2;
  uint16_t* wq   = (uint16_t*)p;  p += (size_t)L_ * 3 * C_ * C_ * 2;
  uint16_t* wp   = (uint16_t*)p;  p += (size_t)L_ * C_ * C_ * 2;
  uint16_t* w1   = (uint16_t*)p;  p += (size_t)L_ * HID_ * C_ * 2;
  uint16_t* w2   = (uint16_t*)p;  p += (size_t)L_ * C_ * HID_ * 2;
  uint16_t* qp   = (uint16_t*)p;  p += (size_t)64 * KPAD_ * 64 * 2;
  uint16_t* kp   = (uint16_t*)p;  p += (size_t)64 * KPAD_ * 64 * 2;
  uint16_t* vtp  = (uint16_t*)p;  p += (size_t)64 * 64 * KPAD_ * 2;
  float*    pbuf = (float*)p;     p += (size_t)4 * PROWS * C_ * 4;
  if ((size_t)(p - (char*)d_ws) > ws_size) return;

  hipMemcpyAsync(xbuf, x_in, (size_t)M_TOK * C_ * sizeof(float),
                 hipMemcpyDeviceToDevice, stream);

  auto cvt = [&](const float* src, uint16_t* dst, size_t n) {
    const int n4 = (int)(n / 4);
    cvt_f32_bf16<<<dim3((n4 + 255) / 256), dim3(256), 0, stream>>>(src, dst, n4);
  };
  cvt(qkv_w,  wq, (size_t)L_ * 3 * C_ * C_);
  cvt(proj_w, wp, (size_t)L_ * C_ * C_);
  cvt(fc1_w,  w1, (size_t)L_ * HID_ * C_);
  cvt(fc2_w,  w2, (size_t)L_ * C_ * HID_);

  // layer-0 ln1 (later layers get it fused into reduce_ln)
  ln_fwd<0><<<dim3(M_TOK), dim3(256), 0, stream>>>(xbuf, ln1_w, ln1_b, hbuf);

  for (int lyr = 0; lyr < L_; ++lyr) {
    // qkv (gemm8p, best observed feed) -> per-head panels
    gemm8p<0, 1><<<dim3(216), dim3(512), 0, stream>>>(
        hbuf, wq + (size_t)lyr * 3 * C_ * C_, qkv_b + (size_t)lyr * 3 * C_,
        nullptr, nullptr, qp, kp, vtp, 3 * C_, C_);
    attn_fwd<<<dim3(64, 17), dim3(256), 0, stream>>>(qp, kp, vtp, hbuf);
    // proj: gemm_s split4 -> pbuf; fused reduce + residual + ln2 -> hbuf
    gemm_s<3, 4><<<dim3(528), dim3(512), 0, stream>>>(
        hbuf, wp + (size_t)lyr * C_ * C_, nullptr, nullptr, pbuf, C_, C_);
    reduce_ln<4, 0><<<dim3(M_TOK), dim3(256), 0, stream>>>(
        pbuf, proj_b + (size_t)lyr * C_, xbuf,
        ln2_w + (size_t)lyr * C_, ln2_b + (size_t)lyr * C_, hbuf);
    // fc1: gemm_s direct, GELU -> big (row-major bf16)
    gemm_s<1, 1><<<dim3(528), dim3(512), 0, stream>>>(
        hbuf, w1 + (size_t)lyr * HID_ * C_, fc1_b + (size_t)lyr * HID_,
        big, nullptr, HID_, C_);
    // fc2: gemm_s split4 -> pbuf; fused reduce + residual + (ln1[next] | final norm)
    gemm_s<3, 4><<<dim3(528), dim3(512), 0, stream>>>(
        big, w2 + (size_t)lyr * C_ * HID_, nullptr, nullptr, pbuf, C_, HID_);
    if (lyr < L_ - 1) {
      reduce_ln<4, 0><<<dim3(M_TOK), dim3(256), 0, stream>>>(
          pbuf, fc2_b + (size_t)lyr * C_, xbuf,
          ln1_w + (size_t)(lyr + 1) * C_, ln1_b + (size_t)(lyr + 1) * C_, hbuf);
    } else {
      reduce_ln<4, 1><<<dim3(M_TOK), dim3(256), 0, stream>>>(
          pbuf, fc2_b + (size_t)lyr * C_, xbuf, norm_w, norm_b, d_out);
    }
  }
}

// Round 12
// 2475.548 us; speedup vs baseline: 1.1191x; 1.0804x over previous
//
#include <hip/hip_runtime.h>
#include <cstdint>
#include <cstddef>

#define B_    4
#define N_TOK 1029
#define C_    1024
#define H_    16
#define L_    8
#define HID_  4096
#define M_TOK (B_*N_TOK)   // 4116
#define MP2_  4352
#define PROWS 4224         // pbuf row stride; gemm_s M extent (33*128)
#define KVB_  128
#define KVT2_ 9
#define KPAD_ 1152

typedef float f32x4 __attribute__((ext_vector_type(4)));
typedef short bf16x8 __attribute__((ext_vector_type(8)));

__device__ __forceinline__ uint16_t f2bf(float f) {
  uint32_t u = __float_as_uint(f);
  u += 0x7fffu + ((u >> 16) & 1u);
  return (uint16_t)(u >> 16);
}

__device__ __forceinline__ void async_copy16(const uint16_t* src, uint16_t* lds_dst) {
  __builtin_amdgcn_global_load_lds(
      (const __attribute__((address_space(1))) void*)src,
      (__attribute__((address_space(3))) void*)lds_dst, 16, 0, 0);
}

__device__ __forceinline__ int swz16(int row, int byte_in_row) {
  return row * 128 + (byte_in_row ^ ((row & 7) << 4));
}

// ---------------- fp32 -> bf16 (row-major) ----------------
__global__ __launch_bounds__(256)
void cvt_f32_bf16(const float* __restrict__ in, uint16_t* __restrict__ out, int n4) {
  int i = blockIdx.x * 256 + threadIdx.x;
  if (i < n4) {
    float4 v = reinterpret_cast<const float4*>(in)[i];
    uint64_t pk = (uint64_t)f2bf(v.x) | ((uint64_t)f2bf(v.y) << 16)
                | ((uint64_t)f2bf(v.z) << 32) | ((uint64_t)f2bf(v.w) << 48);
    reinterpret_cast<uint64_t*>(out)[i] = pk;
  }
}

// ---------------- LayerNorm (standalone; layer-0 ln1 only) ----------------
template<int OUTMODE>   // 0: bf16 out
__global__ __launch_bounds__(256)
void ln_fwd(const float* __restrict__ x, const float* __restrict__ w,
            const float* __restrict__ b, void* __restrict__ outp) {
  const int row = blockIdx.x;
  const int tid = threadIdx.x;
  const float4 v = reinterpret_cast<const float4*>(x + (size_t)row * C_)[tid];
  float s  = v.x + v.y + v.z + v.w;
  float s2 = v.x*v.x + v.y*v.y + v.z*v.z + v.w*v.w;
  #pragma unroll
  for (int d = 1; d < 64; d <<= 1) {
    s  += __shfl_xor(s, d);
    s2 += __shfl_xor(s2, d);
  }
  __shared__ float red[8];
  const int wv = tid >> 6;
  if ((tid & 63) == 0) { red[wv] = s; red[wv + 4] = s2; }
  __syncthreads();
  s  = red[0] + red[1] + red[2] + red[3];
  s2 = red[4] + red[5] + red[6] + red[7];
  const float mu = s * (1.0f / C_);
  const float rs = rsqrtf(fmaxf(s2 * (1.0f / C_) - mu * mu, 0.0f) + 1e-6f);
  const float4 wv4 = reinterpret_cast<const float4*>(w)[tid];
  const float4 bv4 = reinterpret_cast<const float4*>(b)[tid];
  const float o0 = (v.x - mu) * rs * wv4.x + bv4.x;
  const float o1 = (v.y - mu) * rs * wv4.y + bv4.y;
  const float o2 = (v.z - mu) * rs * wv4.z + bv4.z;
  const float o3 = (v.w - mu) * rs * wv4.w + bv4.w;
  uint64_t pk = (uint64_t)f2bf(o0) | ((uint64_t)f2bf(o1) << 16)
              | ((uint64_t)f2bf(o2) << 32) | ((uint64_t)f2bf(o3) << 48);
  reinterpret_cast<uint64_t*>((uint16_t*)outp + (size_t)row * C_)[tid] = pk;
}

// ---------------- fused split-K reduce + residual + LayerNorm ----------------
template<int KCH, int OUT>
__global__ __launch_bounds__(256)
void reduce_ln(const float* __restrict__ pbuf, const float* __restrict__ bias,
               float* __restrict__ xbuf, const float* __restrict__ lw,
               const float* __restrict__ lb, void* __restrict__ outp) {
  const int m = blockIdx.x;
  const int c4 = threadIdx.x;
  float4 s = reinterpret_cast<const float4*>(bias)[c4];
  #pragma unroll
  for (int kc = 0; kc < KCH; ++kc) {
    const float4 pv = reinterpret_cast<const float4*>(pbuf + ((size_t)kc * PROWS + m) * C_)[c4];
    s.x += pv.x; s.y += pv.y; s.z += pv.z; s.w += pv.w;
  }
  float4 x = reinterpret_cast<float4*>(xbuf + (size_t)m * C_)[c4];
  x.x += s.x; x.y += s.y; x.z += s.z; x.w += s.w;
  reinterpret_cast<float4*>(xbuf + (size_t)m * C_)[c4] = x;
  float ss  = x.x + x.y + x.z + x.w;
  float ss2 = x.x*x.x + x.y*x.y + x.z*x.z + x.w*x.w;
  #pragma unroll
  for (int d = 1; d < 64; d <<= 1) {
    ss  += __shfl_xor(ss, d);
    ss2 += __shfl_xor(ss2, d);
  }
  __shared__ float red[8];
  const int wv = c4 >> 6;
  if ((c4 & 63) == 0) { red[wv] = ss; red[wv + 4] = ss2; }
  __syncthreads();
  ss  = red[0] + red[1] + red[2] + red[3];
  ss2 = red[4] + red[5] + red[6] + red[7];
  const float mu = ss * (1.0f / C_);
  const float rs = rsqrtf(fmaxf(ss2 * (1.0f / C_) - mu * mu, 0.0f) + 1e-6f);
  const float4 wv4 = reinterpret_cast<const float4*>(lw)[c4];
  const float4 bv4 = reinterpret_cast<const float4*>(lb)[c4];
  const float o0 = (x.x - mu) * rs * wv4.x + bv4.x;
  const float o1 = (x.y - mu) * rs * wv4.y + bv4.y;
  const float o2 = (x.z - mu) * rs * wv4.z + bv4.z;
  const float o3 = (x.w - mu) * rs * wv4.w + bv4.w;
  if (OUT == 0) {
    uint64_t pk = (uint64_t)f2bf(o0) | ((uint64_t)f2bf(o1) << 16)
                | ((uint64_t)f2bf(o2) << 32) | ((uint64_t)f2bf(o3) << 48);
    reinterpret_cast<uint64_t*>((uint16_t*)outp + (size_t)m * C_)[c4] = pk;
  } else {
    float4 o; o.x = o0; o.y = o1; o.z = o2; o.w = o3;
    reinterpret_cast<float4*>((float*)outp + (size_t)m * C_)[c4] = o;
  }
}

// ---------------- epilogue helper ----------------
// EPI 0: qkv head-split. EPI 1: GELU -> bf16 row-major. EPI 3: fp32 partial -> pbuf.
template<int EPI>
__device__ __forceinline__ void epi_store(int m, int col, float v, int Nn, int kc,
    const float* bias, uint16_t* outb, float* pbuf,
    uint16_t* Qp, uint16_t* Kp, uint16_t* VTp) {
  if (EPI == 3) {
    pbuf[((size_t)kc * PROWS + m) * C_ + col] = v;
  } else if (EPI == 1) {
    const float vb = v + bias[col];
    const float u = -1.5957691216f * (vb + 0.044715f * vb * vb * vb);
    const float g = vb * __builtin_amdgcn_rcpf(1.0f + __expf(u));
    outb[(size_t)m * Nn + col] = f2bf(g);
  } else {  // qkv split
    if (m < M_TOK) {
      const float vb = v + bias[col];
      const int which = col >> 10;
      const int h = (col >> 6) & 15;
      const int d = col & 63;
      const int b = m / N_TOK;
      const int key = m - b * N_TOK;
      const int bh = b * 16 + h;
      if (which == 0)      Qp[((size_t)bh * KPAD_ + key) * 64 + d] = f2bf(vb * 0.125f);
      else if (which == 1) Kp[((size_t)bh * KPAD_ + key) * 64 + d] = f2bf(vb);
      else                 VTp[((size_t)bh * 64 + d) * KPAD_ + key] = f2bf(vb);
    }
  }
}

// ---------------- gemm_s: 128x256, BK=64, 8 waves (2Mx4N, wave-tile 64x64) ------
// Single-buffered 48 KB LDS, 2 blocks/CU (launch_bounds(512,4), acc->AGPR).
// T14 reg-staged prefetch: glob->reg(t+1) issued BEFORE compute(t), written to
// LDS at the top of iter t+1 -> no VMEM wait on the barrier critical path.
template<int EPI, int SPLIT>
__global__ __launch_bounds__(512, 4)
void gemm_s(const uint16_t* __restrict__ A, const uint16_t* __restrict__ W,
            const float* __restrict__ bias, uint16_t* __restrict__ outb,
            float* __restrict__ pbuf, int Nn, int Ktot,
            uint16_t* __restrict__ Qp, uint16_t* __restrict__ Kp,
            uint16_t* __restrict__ VTp) {
  const int nbn = Nn >> 8;
  const int KC = Ktot / SPLIT;
  const int nwg = (int)gridDim.x;
  const int q8 = nwg >> 3, r8 = nwg & 7;
  const int xcd = (int)blockIdx.x & 7, pos = (int)blockIdx.x >> 3;
  const int wgid = (xcd < r8 ? xcd * (q8 + 1) : r8 * (q8 + 1) + (xcd - r8) * q8) + pos;
  const int kc  = wgid / (33 * nbn);
  const int rem = wgid % (33 * nbn);
  const int bm = rem % 33, bn = rem / 33;   // bm fastest: per-XCD blocks share bn

  const int tid = (int)threadIdx.x;
  const int l = tid & 63, w = tid >> 6;
  const int l15 = l & 15, l4 = l >> 4;
  const int wr = w >> 2, wc = w & 3;

  __shared__ char lds[49152];   // A: [0,16K) 128 rows x 128B ; B: [16K,48K) 256 rows

  const uint16_t* Ag = A + (size_t)bm * 128 * Ktot + (size_t)kc * KC;
  const uint16_t* Wg = W + (size_t)bn * 256 * Ktot + (size_t)kc * KC;

  const int srow = tid >> 3;                 // 0..63
  const int schunk = (tid & 7) ^ (srow & 7); // chunk held by slot tid&7
  const int csel0 = ((l4) ^ (l15 & 7)) << 4;
  const int csel1 = ((4 + l4) ^ (l15 & 7)) << 4;

  // prefetch registers (live across compute; acc sits in AGPRs)
  bf16x8 rA0, rA1, rB0, rB1, rB2, rB3;
  auto gload = [&](int toff) {
    rA0 = *(const bf16x8*)(Ag + (size_t)(srow)      * Ktot + toff + schunk * 8);
    rA1 = *(const bf16x8*)(Ag + (size_t)(64 + srow) * Ktot + toff + schunk * 8);
    rB0 = *(const bf16x8*)(Wg + (size_t)(srow)       * Ktot + toff + schunk * 8);
    rB1 = *(const bf16x8*)(Wg + (size_t)(64 + srow)  * Ktot + toff + schunk * 8);
    rB2 = *(const bf16x8*)(Wg + (size_t)(128 + srow) * Ktot + toff + schunk * 8);
    rB3 = *(const bf16x8*)(Wg + (size_t)(192 + srow) * Ktot + toff + schunk * 8);
  };

  f32x4 acc[4][4] = {};
  const int nt = KC >> 6;
  gload(0);
  for (int t = 0; t < nt; ++t) {
    __syncthreads();   // all reads of LDS (tile t-1) done
    // regs -> LDS (compiler inserts the vmcnt waits on the reg deps)
    *(bf16x8*)(lds +         tid * 16) = rA0;
    *(bf16x8*)(lds +  8192 + tid * 16) = rA1;
    *(bf16x8*)(lds + 16384 + tid * 16) = rB0;
    *(bf16x8*)(lds + 24576 + tid * 16) = rB1;
    *(bf16x8*)(lds + 32768 + tid * 16) = rB2;
    *(bf16x8*)(lds + 40960 + tid * 16) = rB3;
    __syncthreads();   // writes visible
    if (t + 1 < nt) gload((t + 1) * 64);   // hidden under compute below
    __builtin_amdgcn_sched_barrier(0);
    #pragma unroll
    for (int kk = 0; kk < 2; ++kk) {
      const int cs = kk ? csel1 : csel0;
      bf16x8 afr[4], bfr[4];
      #pragma unroll
      for (int f = 0; f < 4; ++f)
        afr[f] = *(const bf16x8*)(lds + (wr * 64 + f * 16 + l15) * 128 + cs);
      #pragma unroll
      for (int nf = 0; nf < 4; ++nf)
        bfr[nf] = *(const bf16x8*)(lds + 16384 + (wc * 64 + nf * 16 + l15) * 128 + cs);
      #pragma unroll
      for (int f = 0; f < 4; ++f)
        #pragma unroll
        for (int nf = 0; nf < 4; ++nf)
          acc[f][nf] = __builtin_amdgcn_mfma_f32_16x16x32_bf16(afr[f], bfr[nf], acc[f][nf], 0, 0, 0);
    }
  }

  #pragma unroll
  for (int nf = 0; nf < 4; ++nf) {
    const int col = bn * 256 + wc * 64 + nf * 16 + l15;
    #pragma unroll
    for (int mf = 0; mf < 4; ++mf) {
      const int mb = bm * 128 + wr * 64 + mf * 16 + l4 * 4;
      #pragma unroll
      for (int r = 0; r < 4; ++r)
        epi_store<EPI>(mb + r, col, acc[mf][nf][r], Nn, kc, bias, outb, pbuf,
                       Qp, Kp, VTp);
    }
  }
}

// ---------------- Flash attention (swapped operands, q lane-local) ----------------
__global__ __launch_bounds__(256, 3)
void attn_fwd(const uint16_t* __restrict__ Qp, const uint16_t* __restrict__ Kp,
              const uint16_t* __restrict__ VTp, uint16_t* __restrict__ ob) {
  __shared__ uint16_t Ksm_[KVB_ * 64];
  __shared__ uint16_t Vsm_[64 * KVB_];
  __shared__ uint16_t Psm_[4][16 * 136];

  const int tid = (int)threadIdx.x;
  const int l = tid & 63, w = tid >> 6;
  const int l15 = l & 15, l4 = l >> 4;
  const int bh = (int)blockIdx.x;
  const int qt = (int)blockIdx.y;

  const uint16_t* Kb = Kp + (size_t)bh * KPAD_ * 64;
  const uint16_t* Vb = VTp + (size_t)bh * 64 * KPAD_;

  bf16x8 qf[2];
  {
    const int qrow = qt * 64 + w * 16 + l15;
    const uint16_t* qbase = Qp + ((size_t)bh * KPAD_ + qrow) * 64;
    qf[0] = *(const bf16x8*)(qbase + l4 * 8);
    qf[1] = *(const bf16x8*)(qbase + 32 + l4 * 8);
  }

  float mrow = -1e30f, lrow = 0.0f;
  f32x4 oacc[4] = {};

  const int krow_s = tid >> 3;
  const int kslot_s = (tid & 7) ^ (krow_s & 7);
  const int vd_s = tid >> 4;
  const int vslot_s = (tid & 15) ^ (vd_s & 15);

  for (int kt = 0; kt < KVT2_; ++kt) {
    const int key0 = kt * KVB_;
    __syncthreads();
    #pragma unroll
    for (int it = 0; it < 4; ++it) {
      const int row = it * 32 + krow_s;
      async_copy16(Kb + (size_t)(key0 + row) * 64 + kslot_s * 8,
                   Ksm_ + it * 2048 + tid * 8);
    }
    #pragma unroll
    for (int it = 0; it < 4; ++it) {
      const int d = it * 16 + vd_s;
      async_copy16(Vb + (size_t)d * KPAD_ + key0 + vslot_s * 8,
                   Vsm_ + it * 2048 + tid * 8);
    }
    __syncthreads();

    f32x4 s[8];
    #pragma unroll
    for (int kf = 0; kf < 8; ++kf) s[kf] = f32x4{0.f, 0.f, 0.f, 0.f};
    #pragma unroll
    for (int kk = 0; kk < 2; ++kk) {
      #pragma unroll
      for (int kf = 0; kf < 8; ++kf) {
        const bf16x8 kfrag = *(const bf16x8*)((const char*)Ksm_ + swz16(kf * 16 + l15, kk * 64 + l4 * 16));
        s[kf] = __builtin_amdgcn_mfma_f32_16x16x32_bf16(kfrag, qf[kk], s[kf], 0, 0, 0);
      }
    }
    if (kt == KVT2_ - 1) {
      #pragma unroll
      for (int kf = 0; kf < 8; ++kf)
        #pragma unroll
        for (int r = 0; r < 4; ++r)
          if (key0 + kf * 16 + l4 * 4 + r >= N_TOK) s[kf][r] = -1e30f;
    }
    float pmx = s[0][0];
    #pragma unroll
    for (int kf = 0; kf < 8; ++kf)
      #pragma unroll
      for (int r = 0; r < 4; ++r) pmx = fmaxf(pmx, s[kf][r]);
    pmx = fmaxf(pmx, __shfl_xor(pmx, 16));
    pmx = fmaxf(pmx, __shfl_xor(pmx, 32));
    if (!__all(pmx - mrow <= 8.0f)) {
      const float mi = fmaxf(mrow, pmx);
      const float sc = __expf(mrow - mi);
      mrow = mi;
      lrow *= sc;
      #pragma unroll
      for (int df = 0; df < 4; ++df)
        #pragma unroll
        for (int r = 0; r < 4; ++r) oacc[df][r] *= sc;
    }
    float psum = 0.0f;
    #pragma unroll
    for (int kf = 0; kf < 8; ++kf) {
      const float p0 = __expf(s[kf][0] - mrow);
      const float p1 = __expf(s[kf][1] - mrow);
      const float p2 = __expf(s[kf][2] - mrow);
      const float p3 = __expf(s[kf][3] - mrow);
      psum += (p0 + p1) + (p2 + p3);
      const uint64_t pk = (uint64_t)f2bf(p0) | ((uint64_t)f2bf(p1) << 16)
                        | ((uint64_t)f2bf(p2) << 32) | ((uint64_t)f2bf(p3) << 48);
      *(uint64_t*)(&Psm_[w][l15 * 136 + kf * 16 + l4 * 4]) = pk;
    }
    psum += __shfl_xor(psum, 16);
    psum += __shfl_xor(psum, 32);
    lrow += psum;
    #pragma unroll
    for (int kk = 0; kk < 4; ++kk) {
      const bf16x8 pf = *(const bf16x8*)(&Psm_[w][l15 * 136 + kk * 32 + l4 * 8]);
      #pragma unroll
      for (int df = 0; df < 4; ++df) {
        const int d = df * 16 + l15;
        const bf16x8 vfrag = *(const bf16x8*)(Vsm_ + d * KVB_ + (((kk * 4 + l4) ^ (d & 15)) * 8));
        oacc[df] = __builtin_amdgcn_mfma_f32_16x16x32_bf16(vfrag, pf, oacc[df], 0, 0, 0);
      }
    }
  }

  const int q = qt * 64 + w * 16 + l15;
  if (q < N_TOK) {
    const float inv = 1.0f / lrow;
    const int m = (bh >> 4) * N_TOK + q;
    const int hbase = (bh & 15) * 64;
    #pragma unroll
    for (int df = 0; df < 4; ++df)
      #pragma unroll
      for (int r = 0; r < 4; ++r) {
        const int c = hbase + df * 16 + l4 * 4 + r;
        ob[(size_t)m * C_ + c] = f2bf(oacc[df][r] * inv);
      }
  }
}

extern "C" void kernel_launch(void* const* d_in, const int* in_sizes, int n_in,
                              void* d_out, int out_size, void* d_ws, size_t ws_size,
                              hipStream_t stream) {
  const float* x_in   = (const float*)d_in[0];
  const float* ln1_w  = (const float*)d_in[1];
  const float* ln1_b  = (const float*)d_in[2];
  const float* qkv_w  = (const float*)d_in[3];
  const float* qkv_b  = (const float*)d_in[4];
  const float* proj_w = (const float*)d_in[5];
  const float* proj_b = (const float*)d_in[6];
  const float* ln2_w  = (const float*)d_in[7];
  const float* ln2_b  = (const float*)d_in[8];
  const float* fc1_w  = (const float*)d_in[9];
  const float* fc1_b  = (const float*)d_in[10];
  const float* fc2_w  = (const float*)d_in[11];
  const float* fc2_b  = (const float*)d_in[12];
  const float* norm_w = (const float*)d_in[13];
  const float* norm_b = (const float*)d_in[14];

  char* p = (char*)d_ws;
  float*    xbuf = (float*)p;     p += (size_t)MP2_ * C_ * 4;
  uint16_t* hbuf = (uint16_t*)p;  p += (size_t)MP2_ * C_ * 2;
  uint16_t* big  = (uint16_t*)p;  p += (size_t)MP2_ * HID_ * 2;
  uint16_t* wq   = (uint16_t*)p;  p += (size_t)L_ * 3 * C_ * C_ * 2;
  uint16_t* wp   = (uint16_t*)p;  p += (size_t)L_ * C_ * C_ * 2;
  uint16_t* w1   = (uint16_t*)p;  p += (size_t)L_ * HID_ * C_ * 2;
  uint16_t* w2   = (uint16_t*)p;  p += (size_t)L_ * C_ * HID_ * 2;
  uint16_t* qp   = (uint16_t*)p;  p += (size_t)64 * KPAD_ * 64 * 2;
  uint16_t* kp   = (uint16_t*)p;  p += (size_t)64 * KPAD_ * 64 * 2;
  uint16_t* vtp  = (uint16_t*)p;  p += (size_t)64 * 64 * KPAD_ * 2;
  float*    pbuf = (float*)p;     p += (size_t)4 * PROWS * C_ * 4;
  if ((size_t)(p - (char*)d_ws) > ws_size) return;

  hipMemcpyAsync(xbuf, x_in, (size_t)M_TOK * C_ * sizeof(float),
                 hipMemcpyDeviceToDevice, stream);

  auto cvt = [&](const float* src, uint16_t* dst, size_t n) {
    const int n4 = (int)(n / 4);
    cvt_f32_bf16<<<dim3((n4 + 255) / 256), dim3(256), 0, stream>>>(src, dst, n4);
  };
  cvt(qkv_w,  wq, (size_t)L_ * 3 * C_ * C_);
  cvt(proj_w, wp, (size_t)L_ * C_ * C_);
  cvt(fc1_w,  w1, (size_t)L_ * HID_ * C_);
  cvt(fc2_w,  w2, (size_t)L_ * C_ * HID_);

  // layer-0 ln1 (later layers get it fused into reduce_ln)
  ln_fwd<0><<<dim3(M_TOK), dim3(256), 0, stream>>>(xbuf, ln1_w, ln1_b, hbuf);

  for (int lyr = 0; lyr < L_; ++lyr) {
    // qkv: gemm_s (396 blocks, 2/CU) -> per-head panels
    gemm_s<0, 1><<<dim3(396), dim3(512), 0, stream>>>(
        hbuf, wq + (size_t)lyr * 3 * C_ * C_, qkv_b + (size_t)lyr * 3 * C_,
        nullptr, nullptr, 3 * C_, C_, qp, kp, vtp);
    attn_fwd<<<dim3(64, 17), dim3(256), 0, stream>>>(qp, kp, vtp, hbuf);
    // proj: split2 -> pbuf; fused reduce + residual + ln2 -> hbuf
    gemm_s<3, 2><<<dim3(264), dim3(512), 0, stream>>>(
        hbuf, wp + (size_t)lyr * C_ * C_, nullptr, nullptr, pbuf, C_, C_,
        nullptr, nullptr, nullptr);
    reduce_ln<2, 0><<<dim3(M_TOK), dim3(256), 0, stream>>>(
        pbuf, proj_b + (size_t)lyr * C_, xbuf,
        ln2_w + (size_t)lyr * C_, ln2_b + (size_t)lyr * C_, hbuf);
    // fc1: direct, GELU -> big
    gemm_s<1, 1><<<dim3(528), dim3(512), 0, stream>>>(
        hbuf, w1 + (size_t)lyr * HID_ * C_, fc1_b + (size_t)lyr * HID_,
        big, nullptr, HID_, C_, nullptr, nullptr, nullptr);
    // fc2: split4 -> pbuf; fused reduce + residual + (ln1[next] | final norm)
    gemm_s<3, 4><<<dim3(528), dim3(512), 0, stream>>>(
        big, w2 + (size_t)lyr * C_ * HID_, nullptr, nullptr, pbuf, C_, HID_,
        nullptr, nullptr, nullptr);
    if (lyr < L_ - 1) {
      reduce_ln<4, 0><<<dim3(M_TOK), dim3(256), 0, stream>>>(
          pbuf, fc2_b + (size_t)lyr * C_, xbuf,
          ln1_w + (size_t)(lyr + 1) * C_, ln1_b + (size_t)(lyr + 1) * C_, hbuf);
    } else {
      reduce_ln<4, 1><<<dim3(M_TOK), dim3(256), 0, stream>>>(
          pbuf, fc2_b + (size_t)lyr * C_, xbuf, norm_w, norm_b, d_out);
    }
  }
}